// Round 15
// baseline (407.547 us; speedup 1.0000x reference)
//
#include <hip/hip_runtime.h>
#include <cfloat>

#define N_TOK   32768
#define DIM     64
#define K_CODES 8192
#define NCHK    64                 // 128-code chunks

#define IDX_OFF  (N_TOK * DIM)
#define LOSS_OFF (N_TOK * DIM + N_TOK)

// ws layout (float units): esq 8192 + ehiT 262144 (1MB packed bf16) + parts
#define WS_ESQ   0
#define WS_EHIT  8192
#define WS_PART  270336
// out zq-region scratch (dead until vq_finish):
//   eT (f32 transposed emb) at out+0 : 524288 floats
//   Mm (bf16-up, [chunk][token]) at out+524288 : 2097152 ushorts

#define MRG   2e-5f     // strict slack: bound < every computed fl-d in chunk
#define DINIT 6e-5f     // init slack (covers esq_max + fl-roundings + Mm bf16-up ulp)

typedef __attribute__((ext_vector_type(8)))  short bf16x8;
typedef __attribute__((ext_vector_type(16))) float f32x16;

__device__ inline ushort f2bf(float x) {          // round-to-nearest-even
    unsigned u = __float_as_uint(x);
    return (ushort)((u + 0x7FFFu + ((u >> 16) & 1u)) >> 16);
}
__device__ inline float bf2f(ushort h) { return __uint_as_float(((unsigned)h) << 16); }
__device__ inline ushort f2bf_up(float x) {       // round toward +inf (conservative)
    unsigned u = __float_as_uint(x);
    return (x >= 0.0f) ? (ushort)((u + 0xFFFFu) >> 16) : (ushort)(u >> 16);
}
// sortable pack: lexicographic (d, idx) min == np argmin first-occurrence
__device__ inline unsigned long long packdi(float d, int i) {
    unsigned u = __float_as_uint(d);
    u ^= (u & 0x80000000u) ? 0xFFFFFFFFu : 0x80000000u;
    return ((unsigned long long)u << 32) | (unsigned)i;
}

// ---------------------------------------------------------------------------
// e_sq[k] = numpy-pairwise sum of squares (bitwise np order) — proven R1-R14.
// ---------------------------------------------------------------------------
__global__ __launch_bounds__(256) void esq_kernel(const float* __restrict__ emb,
                                                  float* __restrict__ esq) {
#pragma clang fp contract(off)
    const int tid = threadIdx.x;
    const int q = tid & 7;
    const int code = blockIdx.x * 32 + (tid >> 3);
    const float* row = emb + code * DIM;
    float x = row[q];
    float r = x * x;
#pragma unroll
    for (int m = 1; m < 8; ++m) {
        float y = row[q + 8 * m];
        float sq = y * y;
        r = r + sq;
    }
    r = r + __shfl_xor(r, 1, 64);
    r = r + __shfl_xor(r, 2, 64);
    r = r + __shfl_xor(r, 4, 64);
    if (q == 0) esq[code] = r;
}

// ---------------------------------------------------------------------------
// Pack: ehiT = bf16 e in MFMA-A-fragment order (coalesced b128 A-loads);
// eT = exact f32 transpose eT[j*8192+k] = emb[k][j] (coalesced streaming).
// ---------------------------------------------------------------------------
__global__ __launch_bounds__(256) void pack2(const float* __restrict__ emb,
                                             ushort* __restrict__ ehiT,
                                             float* __restrict__ eT) {
#pragma clang fp contract(off)
    const int k = blockIdx.x * 256 + threadIdx.x;   // 8192 codes
    float v[64];
    {
        const float4* ep = (const float4*)(emb + (size_t)k * DIM);
#pragma unroll
        for (int i = 0; i < 16; ++i) {
            const float4 a = ep[i];
            v[4 * i] = a.x; v[4 * i + 1] = a.y; v[4 * i + 2] = a.z; v[4 * i + 3] = a.w;
        }
    }
#pragma unroll
    for (int j = 0; j < 64; ++j) eT[(size_t)j * K_CODES + k] = v[j];
    const int sc = k >> 7, lc = k & 127;
#pragma unroll
    for (int q = 0; q < 4; ++q)
#pragma unroll
        for (int h = 0; h < 2; ++h) {
            bf16x8 o;
#pragma unroll
            for (int e = 0; e < 8; ++e) o[e] = (short)f2bf(v[16 * q + 8 * h + e]);
            *(bf16x8*)(ehiT + ((((size_t)sc * 4 + q) * 2 + h) * 128 + lc) * 8) = o;
        }
}

// ---------------------------------------------------------------------------
// MFMA sweep v3 (unchanged, passed R13/R14): wave w sweeps chunks 4g+w;
// per-token chunk max via shfl_xor(32); no LDS/barriers; coalesced A-loads.
// ---------------------------------------------------------------------------
__global__ __launch_bounds__(256, 2) void vq_mfma(const float* __restrict__ hid,
                                                  const ushort* __restrict__ ehiT,
                                                  ushort* __restrict__ Mm) {
#pragma clang fp contract(off)
    const int tid = threadIdx.x;
    const int lane = tid & 63;
    const int w = tid >> 6;
    const int h = lane >> 5;
    const int t0 = blockIdx.x * 64;

    bf16x8 z_hi[2][4], z_lo[2][4];
#pragma unroll
    for (int ts = 0; ts < 2; ++ts)
#pragma unroll
    for (int q = 0; q < 4; ++q) {
        const float* zp = hid + (size_t)(t0 + 32 * ts + (lane & 31)) * DIM + 16 * q + 8 * h;
        const float4 u0 = *(const float4*)zp;
        const float4 u1 = *(const float4*)(zp + 4);
        const float zz[8] = {u0.x, u0.y, u0.z, u0.w, u1.x, u1.y, u1.z, u1.w};
        bf16x8 hv, lv;
#pragma unroll
        for (int i = 0; i < 8; ++i) {
            const ushort hb = f2bf(zz[i]);
            hv[i] = (short)hb;
            lv[i] = (short)f2bf(zz[i] - bf2f(hb));
        }
        z_hi[ts][q] = hv; z_lo[ts][q] = lv;
    }

    f32x16 zc;
#pragma unroll
    for (int i = 0; i < 16; ++i) zc[i] = 0.0f;

    for (int g = 0; g < 16; ++g) {
        const int sc = 4 * g + w;
        float wm0 = -3.0e38f, wm1 = -3.0e38f;
#pragma unroll
        for (int r = 0; r < 4; ++r) {
            bf16x8 A[4];
#pragma unroll
            for (int q = 0; q < 4; ++q)
                A[q] = *(const bf16x8*)(ehiT +
                        ((((size_t)sc * 4 + q) * 2 + h) * 128 + 32 * r + (lane & 31)) * 8);
            f32x16 d0, d1;
#pragma unroll
            for (int q = 0; q < 4; ++q) {
                if (q == 0) {
                    d0 = __builtin_amdgcn_mfma_f32_32x32x16_bf16(A[0], z_hi[0][0], zc, 0, 0, 0);
                    d1 = __builtin_amdgcn_mfma_f32_32x32x16_bf16(A[0], z_hi[1][0], zc, 0, 0, 0);
                } else {
                    d0 = __builtin_amdgcn_mfma_f32_32x32x16_bf16(A[q], z_hi[0][q], d0, 0, 0, 0);
                    d1 = __builtin_amdgcn_mfma_f32_32x32x16_bf16(A[q], z_hi[1][q], d1, 0, 0, 0);
                }
                d0 = __builtin_amdgcn_mfma_f32_32x32x16_bf16(A[q], z_lo[0][q], d0, 0, 0, 0);
                d1 = __builtin_amdgcn_mfma_f32_32x32x16_bf16(A[q], z_lo[1][q], d1, 0, 0, 0);
            }
#pragma unroll
            for (int i = 0; i < 16; ++i) {
                wm0 = fmaxf(wm0, d0[i]);
                wm1 = fmaxf(wm1, d1[i]);
            }
        }
        wm0 = fmaxf(wm0, __shfl_xor(wm0, 32, 64));
        wm1 = fmaxf(wm1, __shfl_xor(wm1, 32, 64));
        if (lane < 32) {
            Mm[(size_t)sc * N_TOK + t0 + lane]      = f2bf_up(wm0);
            Mm[(size_t)sc * N_TOK + t0 + 32 + lane] = f2bf_up(wm1);
        }
    }
}

// ---------------------------------------------------------------------------
// Exact selection v6: parallel worklist, 3 barriers total.
// Phase 1: per token, init bound from Mm max; append surviving (tok,chunk)
// items (init-bound pruning is first-index-safe: pruned chunk d's strictly
// exceed best). Phase 2: waves process items independently; R14-proven
// bitwise eval (coalesced eT float2, uniform-LDS z); fold via LDS
// atomicMin(u64) on sortable (d,idx) key == lexicographic min == np argmin.
// ---------------------------------------------------------------------------
__global__ __launch_bounds__(256, 2) void vq_select(const float* __restrict__ hid,
                                                    const float* __restrict__ eT,
                                                    const float* __restrict__ esq,
                                                    const ushort* __restrict__ Mm,
                                                    float* __restrict__ out_idx) {
#pragma clang fp contract(off)
    __shared__ float z_s[64][68];
    __shared__ float zsq_s[64];
    __shared__ unsigned long long key_s[64];
    __shared__ int items[4096];
    __shared__ int cnt;

    const int tid = threadIdx.x;
    const int lane = tid & 63;
    const int w = tid >> 6;
    const int t0 = blockIdx.x * 64;

    // ---- stage z into LDS; init keys/cnt ----
    {
        const int t = tid >> 2;
        const int j4 = (tid & 3) * 4;
        const float4* src = (const float4*)(hid + (size_t)(t0 + t) * DIM);
        float4* dst = (float4*)(&z_s[t][0]);
#pragma unroll
        for (int i = 0; i < 4; ++i) dst[j4 + i] = src[j4 + i];
    }
    if (tid < 64) key_s[tid] = ~0ull;
    if (tid == 0) cnt = 0;
    __syncthreads();

    // ---- phase 1: zsq (numpy pairwise), init bound, survivor items ----
    if (tid < 64) {
        const float* zr = &z_s[tid][0];
        float r[8];
#pragma unroll
        for (int q = 0; q < 8; ++q) {
            float x = zr[q]; r[q] = x * x;
#pragma unroll
            for (int m = 1; m < 8; ++m) {
                float y = zr[q + 8 * m];
                float sq = y * y;
                r[q] = r[q] + sq;
            }
        }
        const float zsq = ((r[0] + r[1]) + (r[2] + r[3])) + ((r[4] + r[5]) + (r[6] + r[7]));
        zsq_s[tid] = zsq;
        float mx = bf2f(Mm[(size_t)0 * N_TOK + t0 + tid]);
#pragma unroll 8
        for (int c = 1; c < NCHK; ++c) mx = fmaxf(mx, bf2f(Mm[(size_t)c * N_TOK + t0 + tid]));
        const float eps = sqrtf(zsq) * 2.5e-6f + 2e-7f;
        const float bD = zsq - 2.0f * mx + 2.0f * eps + DINIT;   // >= true best fl-d
#pragma unroll 8
        for (int c = 0; c < NCHK; ++c) {
            const float m = bf2f(Mm[(size_t)c * N_TOK + t0 + tid]);
            const float bound = fmaf(-2.0f, m + eps, zsq) - MRG;
            if (bound < bD) { const int p = atomicAdd(&cnt, 1); items[p] = (tid << 6) | c; }
        }
    }
    __syncthreads();

    // ---- phase 2: waves process items independently (no barriers) ----
    const int nl = cnt;
    for (int i = w; i < nl; i += 4) {
        const int item = __builtin_amdgcn_readfirstlane(items[i]);
        const int tt = item >> 6;
        const int c = item & 63;
        const int k0 = c * 128 + 2 * lane;
        const float* eb = eT + k0;
        const float2 es2 = *(const float2*)(esq + k0);
        const float zsqT = zsq_s[tt];
        const float4* zp = (const float4*)(&z_s[tt][0]);
        float a0, a1;
        {   // j = 0..3 (j=0 peeled as mul: bitwise head of chain)
            const float4 zv = zp[0];
            float2 e2 = *(const float2*)(eb);
            a0 = zv.x * e2.x; a1 = zv.x * e2.y;
            e2 = *(const float2*)(eb + (size_t)1 * K_CODES);
            a0 = fmaf(zv.y, e2.x, a0); a1 = fmaf(zv.y, e2.y, a1);
            e2 = *(const float2*)(eb + (size_t)2 * K_CODES);
            a0 = fmaf(zv.z, e2.x, a0); a1 = fmaf(zv.z, e2.y, a1);
            e2 = *(const float2*)(eb + (size_t)3 * K_CODES);
            a0 = fmaf(zv.w, e2.x, a0); a1 = fmaf(zv.w, e2.y, a1);
        }
#pragma unroll
        for (int i2 = 1; i2 < 16; ++i2) {
            const float4 zv = zp[i2];
            float2 e2 = *(const float2*)(eb + (size_t)(4 * i2) * K_CODES);
            a0 = fmaf(zv.x, e2.x, a0); a1 = fmaf(zv.x, e2.y, a1);
            e2 = *(const float2*)(eb + (size_t)(4 * i2 + 1) * K_CODES);
            a0 = fmaf(zv.y, e2.x, a0); a1 = fmaf(zv.y, e2.y, a1);
            e2 = *(const float2*)(eb + (size_t)(4 * i2 + 2) * K_CODES);
            a0 = fmaf(zv.z, e2.x, a0); a1 = fmaf(zv.z, e2.y, a1);
            e2 = *(const float2*)(eb + (size_t)(4 * i2 + 3) * K_CODES);
            a0 = fmaf(zv.w, e2.x, a0); a1 = fmaf(zv.w, e2.y, a1);
        }
        const float d0 = fmaf(-2.0f, a0, zsqT + es2.x);
        const float d1 = fmaf(-2.0f, a1, zsqT + es2.y);
        float dl = d0; int il = k0;
        if (d1 < dl) { dl = d1; il = k0 + 1; }       // tie keeps k0 (<k0+1)
#pragma unroll
        for (int m = 1; m < 64; m <<= 1) {
            const float ov = __shfl_xor(dl, m, 64);
            const int   oi = __shfl_xor(il, m, 64);
            if (ov < dl || (ov == dl && oi < il)) { dl = ov; il = oi; }
        }
        if (lane == 0) atomicMin(&key_s[tt], packdi(dl, il));
    }
    __syncthreads();

    if (tid < 64) out_idx[t0 + tid] = (float)(int)(key_s[tid] & 0xFFFFFFFFull);
}

// ---------------------------------------------------------------------------
// Outputs: z_q = h + (q - h), loss partials (proven form).
// ---------------------------------------------------------------------------
__global__ __launch_bounds__(256) void vq_finish(const float* __restrict__ hid,
                                                 const float* __restrict__ emb,
                                                 const float* __restrict__ out_idx,
                                                 float* __restrict__ out_zq,
                                                 float* __restrict__ partials) {
#pragma clang fp contract(off)
    __shared__ float lred[4];
    const int tid = threadIdx.x;
    const int t = blockIdx.x * 256 + tid;

    const int bi = (int)out_idx[t];

    const float4* q4 = (const float4*)(emb + (size_t)bi * DIM);
    const float4* h4 = (const float4*)(hid + (size_t)t * DIM);
    float4* o4 = (float4*)(out_zq + (size_t)t * DIM);
    float lsum = 0.f;
#pragma unroll
    for (int i = 0; i < 16; ++i) {
        const float4 q = q4[i];
        const float4 h = h4[i];
        float4 zq;
        float dx;
        dx = q.x - h.x; zq.x = h.x + dx; lsum += dx * dx;
        dx = q.y - h.y; zq.y = h.y + dx; lsum += dx * dx;
        dx = q.z - h.z; zq.z = h.z + dx; lsum += dx * dx;
        dx = q.w - h.w; zq.w = h.w + dx; lsum += dx * dx;
        o4[i] = zq;
    }

#pragma unroll
    for (int off = 32; off >= 1; off >>= 1) lsum += __shfl_xor(lsum, off, 64);
    const int wid = tid >> 6;
    if ((tid & 63) == 0) lred[wid] = lsum;
    __syncthreads();
    if (tid == 0) partials[blockIdx.x] = (lred[0] + lred[1]) + (lred[2] + lred[3]);
}

__global__ __launch_bounds__(128) void loss_kernel(const float* __restrict__ partials,
                                                   float* __restrict__ out_loss) {
#pragma clang fp contract(off)
    __shared__ float s[128];
    const int t = threadIdx.x;
    s[t] = partials[t];
    __syncthreads();
    for (int off = 64; off >= 1; off >>= 1) {
        if (t < off) s[t] = s[t] + s[t + off];
        __syncthreads();
    }
    if (t == 0) {
        const float m = s[0] * (1.0f / 2097152.0f);  // exact: /2^21
        out_loss[0] = m + 0.25f * m;
    }
}

extern "C" void kernel_launch(void* const* d_in, const int* in_sizes, int n_in,
                              void* d_out, int out_size, void* d_ws, size_t ws_size,
                              hipStream_t stream) {
    const float* hid = (const float*)d_in[0];
    const float* emb = (const float*)d_in[1];
    float* out = (float*)d_out;
    float* ws  = (float*)d_ws;
    float*  esq   = ws + WS_ESQ;
    ushort* ehiT  = (ushort*)(ws + WS_EHIT);
    float*  parts = ws + WS_PART;
    float*  eT    = out;                               // zq-region scratch
    ushort* Mm    = (ushort*)(out + 524288);           // zq-region scratch

    esq_kernel<<<K_CODES / 32, 256, 0, stream>>>(emb, esq);
    pack2<<<K_CODES / 256, 256, 0, stream>>>(emb, ehiT, eT);
    vq_mfma<<<N_TOK / 64, 256, 0, stream>>>(hid, ehiT, Mm);
    vq_select<<<N_TOK / 64, 256, 0, stream>>>(hid, eT, esq, Mm, out + IDX_OFF);
    vq_finish<<<N_TOK / 256, 256, 0, stream>>>(hid, emb, out + IDX_OFF, out, parts);
    loss_kernel<<<1, 128, 0, stream>>>(parts, out + LOSS_OFF);
}

// Round 16
// 216.240 us; speedup vs baseline: 1.8847x; 1.8847x over previous
//
#include <hip/hip_runtime.h>
#include <cfloat>

#define N_TOK   32768
#define DIM     64
#define K_CODES 8192
#define NCHK    64                 // 128-code chunks

#define IDX_OFF  (N_TOK * DIM)
#define LOSS_OFF (N_TOK * DIM + N_TOK)

// ws layout (float units): esq 8192 + ehiT 262144 (1MB packed bf16) + parts
#define WS_ESQ   0
#define WS_EHIT  8192
#define WS_PART  270336
// out zq-region scratch (dead until vq_finish):
//   eT (f32 transposed emb) at out+0 : 524288 floats
//   Mm (bf16-up, [chunk][token]) at out+524288 : 2097152 ushorts

#define MRG   2e-5f     // strict slack: bound < every computed fl-d in chunk
#define DINIT 6e-5f     // init slack (covers esq_max + fl-roundings + Mm bf16-up ulp)

typedef __attribute__((ext_vector_type(8)))  short bf16x8;
typedef __attribute__((ext_vector_type(16))) float f32x16;

__device__ inline ushort f2bf(float x) {          // round-to-nearest-even
    unsigned u = __float_as_uint(x);
    return (ushort)((u + 0x7FFFu + ((u >> 16) & 1u)) >> 16);
}
__device__ inline float bf2f(ushort h) { return __uint_as_float(((unsigned)h) << 16); }
__device__ inline ushort f2bf_up(float x) {       // round toward +inf (conservative)
    unsigned u = __float_as_uint(x);
    return (x >= 0.0f) ? (ushort)((u + 0xFFFFu) >> 16) : (ushort)(u >> 16);
}
// sortable pack: lexicographic (d, idx) min == np argmin first-occurrence
__device__ inline unsigned long long packdi(float d, int i) {
    unsigned u = __float_as_uint(d);
    u ^= (u & 0x80000000u) ? 0xFFFFFFFFu : 0x80000000u;
    return ((unsigned long long)u << 32) | (unsigned)i;
}

// ---------------------------------------------------------------------------
// e_sq[k] = numpy-pairwise sum of squares (bitwise np order) — proven R1-R15.
// ---------------------------------------------------------------------------
__global__ __launch_bounds__(256) void esq_kernel(const float* __restrict__ emb,
                                                  float* __restrict__ esq) {
#pragma clang fp contract(off)
    const int tid = threadIdx.x;
    const int q = tid & 7;
    const int code = blockIdx.x * 32 + (tid >> 3);
    const float* row = emb + code * DIM;
    float x = row[q];
    float r = x * x;
#pragma unroll
    for (int m = 1; m < 8; ++m) {
        float y = row[q + 8 * m];
        float sq = y * y;
        r = r + sq;
    }
    r = r + __shfl_xor(r, 1, 64);
    r = r + __shfl_xor(r, 2, 64);
    r = r + __shfl_xor(r, 4, 64);
    if (q == 0) esq[code] = r;
}

// ---------------------------------------------------------------------------
// Pack: ehiT = bf16 e in MFMA-A-fragment order (coalesced b128 A-loads);
// eT = exact f32 transpose eT[j*8192+k] = emb[k][j] (coalesced streaming).
// ---------------------------------------------------------------------------
__global__ __launch_bounds__(256) void pack2(const float* __restrict__ emb,
                                             ushort* __restrict__ ehiT,
                                             float* __restrict__ eT) {
#pragma clang fp contract(off)
    const int k = blockIdx.x * 256 + threadIdx.x;   // 8192 codes
    float v[64];
    {
        const float4* ep = (const float4*)(emb + (size_t)k * DIM);
#pragma unroll
        for (int i = 0; i < 16; ++i) {
            const float4 a = ep[i];
            v[4 * i] = a.x; v[4 * i + 1] = a.y; v[4 * i + 2] = a.z; v[4 * i + 3] = a.w;
        }
    }
#pragma unroll
    for (int j = 0; j < 64; ++j) eT[(size_t)j * K_CODES + k] = v[j];
    const int sc = k >> 7, lc = k & 127;
#pragma unroll
    for (int q = 0; q < 4; ++q)
#pragma unroll
        for (int h = 0; h < 2; ++h) {
            bf16x8 o;
#pragma unroll
            for (int e = 0; e < 8; ++e) o[e] = (short)f2bf(v[16 * q + 8 * h + e]);
            *(bf16x8*)(ehiT + ((((size_t)sc * 4 + q) * 2 + h) * 128 + lc) * 8) = o;
        }
}

// ---------------------------------------------------------------------------
// MFMA sweep v3 (unchanged, passed R13-R15): wave w sweeps chunks 4g+w;
// per-token chunk max via shfl_xor(32); no LDS/barriers; coalesced A-loads.
// ---------------------------------------------------------------------------
__global__ __launch_bounds__(256, 2) void vq_mfma(const float* __restrict__ hid,
                                                  const ushort* __restrict__ ehiT,
                                                  ushort* __restrict__ Mm) {
#pragma clang fp contract(off)
    const int tid = threadIdx.x;
    const int lane = tid & 63;
    const int w = tid >> 6;
    const int h = lane >> 5;
    const int t0 = blockIdx.x * 64;

    bf16x8 z_hi[2][4], z_lo[2][4];
#pragma unroll
    for (int ts = 0; ts < 2; ++ts)
#pragma unroll
    for (int q = 0; q < 4; ++q) {
        const float* zp = hid + (size_t)(t0 + 32 * ts + (lane & 31)) * DIM + 16 * q + 8 * h;
        const float4 u0 = *(const float4*)zp;
        const float4 u1 = *(const float4*)(zp + 4);
        const float zz[8] = {u0.x, u0.y, u0.z, u0.w, u1.x, u1.y, u1.z, u1.w};
        bf16x8 hv, lv;
#pragma unroll
        for (int i = 0; i < 8; ++i) {
            const ushort hb = f2bf(zz[i]);
            hv[i] = (short)hb;
            lv[i] = (short)f2bf(zz[i] - bf2f(hb));
        }
        z_hi[ts][q] = hv; z_lo[ts][q] = lv;
    }

    f32x16 zc;
#pragma unroll
    for (int i = 0; i < 16; ++i) zc[i] = 0.0f;

    for (int g = 0; g < 16; ++g) {
        const int sc = 4 * g + w;
        float wm0 = -3.0e38f, wm1 = -3.0e38f;
#pragma unroll
        for (int r = 0; r < 4; ++r) {
            bf16x8 A[4];
#pragma unroll
            for (int q = 0; q < 4; ++q)
                A[q] = *(const bf16x8*)(ehiT +
                        ((((size_t)sc * 4 + q) * 2 + h) * 128 + 32 * r + (lane & 31)) * 8);
            f32x16 d0, d1;
#pragma unroll
            for (int q = 0; q < 4; ++q) {
                if (q == 0) {
                    d0 = __builtin_amdgcn_mfma_f32_32x32x16_bf16(A[0], z_hi[0][0], zc, 0, 0, 0);
                    d1 = __builtin_amdgcn_mfma_f32_32x32x16_bf16(A[0], z_hi[1][0], zc, 0, 0, 0);
                } else {
                    d0 = __builtin_amdgcn_mfma_f32_32x32x16_bf16(A[q], z_hi[0][q], d0, 0, 0, 0);
                    d1 = __builtin_amdgcn_mfma_f32_32x32x16_bf16(A[q], z_hi[1][q], d1, 0, 0, 0);
                }
                d0 = __builtin_amdgcn_mfma_f32_32x32x16_bf16(A[q], z_lo[0][q], d0, 0, 0, 0);
                d1 = __builtin_amdgcn_mfma_f32_32x32x16_bf16(A[q], z_lo[1][q], d1, 0, 0, 0);
            }
#pragma unroll
            for (int i = 0; i < 16; ++i) {
                wm0 = fmaxf(wm0, d0[i]);
                wm1 = fmaxf(wm1, d1[i]);
            }
        }
        wm0 = fmaxf(wm0, __shfl_xor(wm0, 32, 64));
        wm1 = fmaxf(wm1, __shfl_xor(wm1, 32, 64));
        if (lane < 32) {
            Mm[(size_t)sc * N_TOK + t0 + lane]      = f2bf_up(wm0);
            Mm[(size_t)sc * N_TOK + t0 + 32 + lane] = f2bf_up(wm1);
        }
    }
}

// ---------------------------------------------------------------------------
// Exact selection v7: R15 worklist (3 barriers) + software-pipelined eval:
// two 8x float2 register buffers, LOADG(next) issued before FMAG(cur) —
// >=8 e-loads in flight under the FMA chain (R15 had ~1: latency collapse).
// Chain order strictly j=0..63 (bitwise == R14/R15). Phase 1 wave-parallel.
// Fold via LDS atomicMin(u64) sortable (d,idx) key == np first-occurrence.
// ---------------------------------------------------------------------------
__global__ __launch_bounds__(256, 2) void vq_select(const float* __restrict__ hid,
                                                    const float* __restrict__ eT,
                                                    const float* __restrict__ esq,
                                                    const ushort* __restrict__ Mm,
                                                    float* __restrict__ out_idx) {
#pragma clang fp contract(off)
    __shared__ float z_s[64][68];
    __shared__ float zsq_s[64];
    __shared__ float eps_s[64];
    __shared__ float bD_s[64];
    __shared__ float mxw[4][64];
    __shared__ unsigned long long key_s[64];
    __shared__ int items[4096];
    __shared__ int cnt;

    const int tid = threadIdx.x;
    const int lane = tid & 63;
    const int w = tid >> 6;
    const int t0 = blockIdx.x * 64;

    // ---- stage z into LDS; init keys/cnt ----
    {
        const int t = tid >> 2;
        const int j4 = (tid & 3) * 4;
        const float4* src = (const float4*)(hid + (size_t)(t0 + t) * DIM);
        float4* dst = (float4*)(&z_s[t][0]);
#pragma unroll
        for (int i = 0; i < 4; ++i) dst[j4 + i] = src[j4 + i];
    }
    if (tid < 64) key_s[tid] = ~0ull;
    if (tid == 0) cnt = 0;
    __syncthreads();

    // ---- phase 1a: wave-parallel partial max over 16 chunks; zsq (wave 0) ----
    {
        float pm = bf2f(Mm[(size_t)(16 * w) * N_TOK + t0 + lane]);
#pragma unroll 5
        for (int c = 16 * w + 1; c < 16 * w + 16; ++c)
            pm = fmaxf(pm, bf2f(Mm[(size_t)c * N_TOK + t0 + lane]));
        mxw[w][lane] = pm;
    }
    if (tid < 64) {
        const float* zr = &z_s[tid][0];
        float r[8];
#pragma unroll
        for (int q = 0; q < 8; ++q) {
            float x = zr[q]; r[q] = x * x;
#pragma unroll
            for (int m = 1; m < 8; ++m) {
                float y = zr[q + 8 * m];
                float sq = y * y;
                r[q] = r[q] + sq;
            }
        }
        zsq_s[tid] = ((r[0] + r[1]) + (r[2] + r[3])) + ((r[4] + r[5]) + (r[6] + r[7]));
    }
    __syncthreads();
    if (tid < 64) {
        const float mx = fmaxf(fmaxf(mxw[0][tid], mxw[1][tid]),
                               fmaxf(mxw[2][tid], mxw[3][tid]));
        const float zsq = zsq_s[tid];
        const float eps = sqrtf(zsq) * 2.5e-6f + 2e-7f;
        eps_s[tid] = eps;
        bD_s[tid] = zsq - 2.0f * mx + 2.0f * eps + DINIT;   // >= true best fl-d
    }
    __syncthreads();

    // ---- phase 1b: wave-parallel bound check, append survivor items ----
    {
        const float zsq = zsq_s[lane];
        const float eps = eps_s[lane];
        const float bD = bD_s[lane];
#pragma unroll 4
        for (int c = 16 * w; c < 16 * w + 16; ++c) {
            const float m = bf2f(Mm[(size_t)c * N_TOK + t0 + lane]);
            const float bound = fmaf(-2.0f, m + eps, zsq) - MRG;
            if (bound < bD) { const int p = atomicAdd(&cnt, 1); items[p] = (lane << 6) | c; }
        }
    }
    __syncthreads();

    // ---- phase 2: waves process items independently (no barriers) ----
    const int nl = cnt;
    for (int i = w; i < nl; i += 4) {
        const int item = __builtin_amdgcn_readfirstlane(items[i]);
        const int tt = item >> 6;
        const int c = item & 63;
        const int k0 = c * 128 + 2 * lane;
        const float* eb = eT + k0;
        const float2 es2 = *(const float2*)(esq + k0);
        const float zsqT = zsq_s[tt];
        const float4* zp = (const float4*)(&z_s[tt][0]);

        float2 bA[8], bB[8];
        float a0, a1;
#define LOADG(B, G) { _Pragma("unroll") \
    for (int j = 0; j < 8; ++j) \
        B[j] = *(const float2*)(eb + (size_t)(8 * (G) + j) * K_CODES); }
#define FMAG(B, G) { \
    const float4 zva = zp[2 * (G)]; \
    a0 = fmaf(zva.x, B[0].x, a0); a1 = fmaf(zva.x, B[0].y, a1); \
    a0 = fmaf(zva.y, B[1].x, a0); a1 = fmaf(zva.y, B[1].y, a1); \
    a0 = fmaf(zva.z, B[2].x, a0); a1 = fmaf(zva.z, B[2].y, a1); \
    a0 = fmaf(zva.w, B[3].x, a0); a1 = fmaf(zva.w, B[3].y, a1); \
    const float4 zvb = zp[2 * (G) + 1]; \
    a0 = fmaf(zvb.x, B[4].x, a0); a1 = fmaf(zvb.x, B[4].y, a1); \
    a0 = fmaf(zvb.y, B[5].x, a0); a1 = fmaf(zvb.y, B[5].y, a1); \
    a0 = fmaf(zvb.z, B[6].x, a0); a1 = fmaf(zvb.z, B[6].y, a1); \
    a0 = fmaf(zvb.w, B[7].x, a0); a1 = fmaf(zvb.w, B[7].y, a1); }

        LOADG(bA, 0)
        LOADG(bB, 1)
        {   // group 0, j=0 peeled as mul (bitwise head of chain)
            const float4 zva = zp[0];
            a0 = zva.x * bA[0].x;          a1 = zva.x * bA[0].y;
            a0 = fmaf(zva.y, bA[1].x, a0); a1 = fmaf(zva.y, bA[1].y, a1);
            a0 = fmaf(zva.z, bA[2].x, a0); a1 = fmaf(zva.z, bA[2].y, a1);
            a0 = fmaf(zva.w, bA[3].x, a0); a1 = fmaf(zva.w, bA[3].y, a1);
            const float4 zvb = zp[1];
            a0 = fmaf(zvb.x, bA[4].x, a0); a1 = fmaf(zvb.x, bA[4].y, a1);
            a0 = fmaf(zvb.y, bA[5].x, a0); a1 = fmaf(zvb.y, bA[5].y, a1);
            a0 = fmaf(zvb.z, bA[6].x, a0); a1 = fmaf(zvb.z, bA[6].y, a1);
            a0 = fmaf(zvb.w, bA[7].x, a0); a1 = fmaf(zvb.w, bA[7].y, a1);
        }
        LOADG(bA, 2) FMAG(bB, 1)
        LOADG(bB, 3) FMAG(bA, 2)
        LOADG(bA, 4) FMAG(bB, 3)
        LOADG(bB, 5) FMAG(bA, 4)
        LOADG(bA, 6) FMAG(bB, 5)
        LOADG(bB, 7) FMAG(bA, 6)
        FMAG(bB, 7)
#undef LOADG
#undef FMAG

        const float d0 = fmaf(-2.0f, a0, zsqT + es2.x);
        const float d1 = fmaf(-2.0f, a1, zsqT + es2.y);
        float dl = d0; int il = k0;
        if (d1 < dl) { dl = d1; il = k0 + 1; }       // tie keeps k0 (<k0+1)
#pragma unroll
        for (int m = 1; m < 64; m <<= 1) {
            const float ov = __shfl_xor(dl, m, 64);
            const int   oi = __shfl_xor(il, m, 64);
            if (ov < dl || (ov == dl && oi < il)) { dl = ov; il = oi; }
        }
        if (lane == 0) atomicMin(&key_s[tt], packdi(dl, il));
    }
    __syncthreads();

    if (tid < 64) out_idx[t0 + tid] = (float)(int)(key_s[tid] & 0xFFFFFFFFull);
}

// ---------------------------------------------------------------------------
// Outputs: z_q = h + (q - h), loss partials (proven form).
// ---------------------------------------------------------------------------
__global__ __launch_bounds__(256) void vq_finish(const float* __restrict__ hid,
                                                 const float* __restrict__ emb,
                                                 const float* __restrict__ out_idx,
                                                 float* __restrict__ out_zq,
                                                 float* __restrict__ partials) {
#pragma clang fp contract(off)
    __shared__ float lred[4];
    const int tid = threadIdx.x;
    const int t = blockIdx.x * 256 + tid;

    const int bi = (int)out_idx[t];

    const float4* q4 = (const float4*)(emb + (size_t)bi * DIM);
    const float4* h4 = (const float4*)(hid + (size_t)t * DIM);
    float4* o4 = (float4*)(out_zq + (size_t)t * DIM);
    float lsum = 0.f;
#pragma unroll
    for (int i = 0; i < 16; ++i) {
        const float4 q = q4[i];
        const float4 h = h4[i];
        float4 zq;
        float dx;
        dx = q.x - h.x; zq.x = h.x + dx; lsum += dx * dx;
        dx = q.y - h.y; zq.y = h.y + dx; lsum += dx * dx;
        dx = q.z - h.z; zq.z = h.z + dx; lsum += dx * dx;
        dx = q.w - h.w; zq.w = h.w + dx; lsum += dx * dx;
        o4[i] = zq;
    }

#pragma unroll
    for (int off = 32; off >= 1; off >>= 1) lsum += __shfl_xor(lsum, off, 64);
    const int wid = tid >> 6;
    if ((tid & 63) == 0) lred[wid] = lsum;
    __syncthreads();
    if (tid == 0) partials[blockIdx.x] = (lred[0] + lred[1]) + (lred[2] + lred[3]);
}

__global__ __launch_bounds__(128) void loss_kernel(const float* __restrict__ partials,
                                                   float* __restrict__ out_loss) {
#pragma clang fp contract(off)
    __shared__ float s[128];
    const int t = threadIdx.x;
    s[t] = partials[t];
    __syncthreads();
    for (int off = 64; off >= 1; off >>= 1) {
        if (t < off) s[t] = s[t] + s[t + off];
        __syncthreads();
    }
    if (t == 0) {
        const float m = s[0] * (1.0f / 2097152.0f);  // exact: /2^21
        out_loss[0] = m + 0.25f * m;
    }
}

extern "C" void kernel_launch(void* const* d_in, const int* in_sizes, int n_in,
                              void* d_out, int out_size, void* d_ws, size_t ws_size,
                              hipStream_t stream) {
    const float* hid = (const float*)d_in[0];
    const float* emb = (const float*)d_in[1];
    float* out = (float*)d_out;
    float* ws  = (float*)d_ws;
    float*  esq   = ws + WS_ESQ;
    ushort* ehiT  = (ushort*)(ws + WS_EHIT);
    float*  parts = ws + WS_PART;
    float*  eT    = out;                               // zq-region scratch
    ushort* Mm    = (ushort*)(out + 524288);           // zq-region scratch

    esq_kernel<<<K_CODES / 32, 256, 0, stream>>>(emb, esq);
    pack2<<<K_CODES / 256, 256, 0, stream>>>(emb, ehiT, eT);
    vq_mfma<<<N_TOK / 64, 256, 0, stream>>>(hid, ehiT, Mm);
    vq_select<<<N_TOK / 64, 256, 0, stream>>>(hid, eT, esq, Mm, out + IDX_OFF);
    vq_finish<<<N_TOK / 256, 256, 0, stream>>>(hid, emb, out + IDX_OFF, out, parts);
    loss_kernel<<<1, 128, 0, stream>>>(parts, out + LOSS_OFF);
}